// Round 5
// baseline (228.661 us; speedup 1.0000x reference)
//
#include <hip/hip_runtime.h>

// Shapes (fixed): B=2, S=2048, D=1024, H=16, hd=64. M = B*S = 4096.
// ws layout (bf16 elems): qb[4M] | xb[4M] | wt[4M] | qkv[4096*3072] | vt[2][16][64][2048] | ctx[4M]

typedef __bf16 bf16_t;
typedef __attribute__((ext_vector_type(8))) __bf16 bf16x8;
typedef __attribute__((ext_vector_type(4))) __bf16 bf16x4;
typedef __attribute__((ext_vector_type(4))) float f32x4;

#define SCALE_LOG2E 0.045084220027780106f  // log2(e)/32
#define FIXED_MAX 8.0f

__device__ __forceinline__ void async_load16(const void* g, void* l) {
  __builtin_amdgcn_global_load_lds(
      (const __attribute__((address_space(1))) void*)g,
      (__attribute__((address_space(3))) void*)l, 16, 0, 0);
}

// ---- fused prep: blocks 0..4095 cast x/q_in; blocks 4096..5119 cast+transpose weights ----
__global__ void prep(const float* __restrict__ x, const float* __restrict__ q,
                     const float* __restrict__ w0, const float* __restrict__ w1,
                     const float* __restrict__ w2, const float* __restrict__ w3,
                     bf16_t* __restrict__ xb, bf16_t* __restrict__ qb,
                     bf16_t* __restrict__ wt) {
  const int bid = blockIdx.x;
  if (bid < 4096) {
    const float* src = (bid >= 2048) ? q : x;
    bf16_t* dst = (bid >= 2048) ? qb : xb;
    const size_t i = ((size_t)(bid & 2047) * 256 + threadIdx.x) * 8;
    float4 v0 = *(const float4*)(src + i);
    float4 v1 = *(const float4*)(src + i + 4);
    bf16x8 o;
    o[0] = (bf16_t)v0.x; o[1] = (bf16_t)v0.y; o[2] = (bf16_t)v0.z; o[3] = (bf16_t)v0.w;
    o[4] = (bf16_t)v1.x; o[5] = (bf16_t)v1.y; o[6] = (bf16_t)v1.z; o[7] = (bf16_t)v1.w;
    *(bf16x8*)(dst + i) = o;
  } else {
    const int wb = bid - 4096;
    const int z = wb >> 8;
    const float* W = z == 0 ? w0 : z == 1 ? w1 : z == 2 ? w2 : w3;
    bf16_t* dst = wt + (size_t)z * 1048576;
    const int r0 = ((wb >> 4) & 15) * 64, c0 = (wb & 15) * 64;
    __shared__ bf16_t t[64][72];
#pragma unroll
    for (int i = 0; i < 16; ++i) {
      int flat = i * 256 + threadIdx.x;
      int r = flat >> 6, c = flat & 63;
      t[c][r] = (bf16_t)W[(size_t)(r0 + r) * 1024 + c0 + c];
    }
    __syncthreads();
    const int c = threadIdx.x >> 2, seg = (threadIdx.x & 3) * 16;
    bf16x8 a = *(const bf16x8*)&t[c][seg];
    bf16x8 b = *(const bf16x8*)&t[c][seg + 8];
    bf16_t* drow = dst + (size_t)(c0 + c) * 1024 + r0 + seg;
    *(bf16x8*)drow = a;
    *(bf16x8*)(drow + 8) = b;
  }
}

// ---- GEMM (m97-style, BK=32). MODE 0: fused QKV 128x128. MODE 2: out GEMM 128x64, fp32. ----
template <int MODE>
__global__ __launch_bounds__(256, MODE == 2 ? 4 : 2) void gemm128(
    const bf16_t* __restrict__ Aq, const bf16_t* __restrict__ Ax,
    const bf16_t* __restrict__ Bt,
    bf16_t* __restrict__ Cq, bf16_t* __restrict__ Cvt, float* __restrict__ Cf) {
  constexpr int K = 1024;
  constexpr int NT = (MODE == 2) ? 2 : 4;
  constexpr int NROWS = NT * 32;
  const int n0 = blockIdx.x * NROWS;
  const int m0 = blockIdx.y * 128;
  const bf16_t* A = (MODE == 0 && n0 >= 1024) ? Ax : Aq;

  __shared__ bf16_t lA[128 * 32];
  __shared__ bf16_t lB[NROWS * 32];

  const int tid = threadIdx.x;
  const int w = tid >> 6, l = tid & 63;
  const int wm = (w & 1) * 64, wn = (w >> 1) * (NT * 16);
  const int sr = l >> 2;
  const int sk = (l & 3) * 8;
  const int fr = l & 15, fc = (l >> 4) * 8;

  f32x4 acc[4][NT] = {};

  for (int kt = 0; kt < K; kt += 32) {
    __syncthreads();
#pragma unroll
    for (int c = 0; c < 2; ++c) {
      const int ch = w * 2 + c;
      async_load16(A + (size_t)(m0 + ch * 16 + sr) * K + kt + sk, &lA[ch * 512]);
      if (NT == 4 || c == 0) {
        const int bch = (NT == 4) ? ch : w;
        async_load16(Bt + (size_t)(n0 + bch * 16 + sr) * K + kt + sk, &lB[bch * 512]);
      }
    }
    __syncthreads();
    bf16x8 af[4], bfr[NT];
#pragma unroll
    for (int i = 0; i < 4; ++i) af[i] = *(const bf16x8*)&lA[(wm + i * 16 + fr) * 32 + fc];
#pragma unroll
    for (int j = 0; j < NT; ++j) bfr[j] = *(const bf16x8*)&lB[(wn + j * 16 + fr) * 32 + fc];
#pragma unroll
    for (int i = 0; i < 4; ++i)
#pragma unroll
      for (int j = 0; j < NT; ++j)
        acc[i][j] = __builtin_amdgcn_mfma_f32_16x16x32_bf16(af[i], bfr[j], acc[i][j], 0, 0, 0);
  }

  if (MODE == 2) {
#pragma unroll
    for (int i = 0; i < 4; ++i) {
      const int m = m0 + wm + i * 16 + (l >> 4) * 4;
#pragma unroll
      for (int j = 0; j < NT; ++j) {
        const int n = n0 + wn + j * 16 + fr;
#pragma unroll
        for (int r = 0; r < 4; ++r) Cf[(size_t)(m + r) * 1024 + n] = acc[i][j][r];
      }
    }
  } else if (n0 < 2048) {
#pragma unroll
    for (int i = 0; i < 4; ++i) {
      const int m = m0 + wm + i * 16 + (l >> 4) * 4;
#pragma unroll
      for (int j = 0; j < NT; ++j) {
        const int n = n0 + wn + j * 16 + fr;
#pragma unroll
        for (int r = 0; r < 4; ++r) Cq[(size_t)(m + r) * 3072 + n] = (bf16_t)acc[i][j][r];
      }
    }
  } else {
#pragma unroll
    for (int i = 0; i < 4; ++i) {
      const int mb = m0 + wm + i * 16 + (l >> 4) * 4;
      const int bb = mb >> 11, ss = mb & 2047;
#pragma unroll
      for (int j = 0; j < NT; ++j) {
        const int nn = n0 - 2048 + wn + j * 16 + fr;
        const int hh = nn >> 6, dd = nn & 63;
        bf16x4 pk;
#pragma unroll
        for (int r = 0; r < 4; ++r) pk[r] = (bf16_t)acc[i][j][r];
        *(bf16x4*)(Cvt + (size_t)((bb * 16 + hh) * 64 + dd) * 2048 + ss) = pk;
      }
    }
  }
}

// ---- flash attention v3: 32-q blocks, waves split keys, register-direct K/V, no loop barriers ----
// grid (32 bh, 64 q-tiles). All 4 waves share the block's 32 q; wave w handles key-tiles kt≡w (mod 4),
// accumulating partial O^T/li; one LDS reduction at the end. K frags double-buffered in regs.
__global__ __launch_bounds__(256, 2) void attn32(const bf16_t* __restrict__ qkv,
                                                 const bf16_t* __restrict__ vt,
                                                 bf16_t* __restrict__ ctx) {
  const int y = blockIdx.y;
  // class-balanced qt permutation: k=y>>3, j=y&7; stride-8 classes sum to a constant
  const int kk = y >> 3, jj = y & 7;
  const int qt = 63 - ((kk << 3) | ((kk & 1) ? (7 - jj) : jj));
  const int bh = blockIdx.x;
  const int b = bh >> 4, h = bh & 15;
  const int tid = threadIdx.x, w = tid >> 6, l = tid & 63;
  const int fr = l & 15, fq = l >> 4;

  __shared__ __align__(16) bf16_t lP[4][32 * 72];   // per-wave P^T, q-major
  __shared__ __align__(16) float lRed[4][32][68];   // per-wave O^T partials + li

  const int q0 = qt * 32;

  bf16x8 qf[2][2];
#pragma unroll
  for (int u = 0; u < 2; ++u)
#pragma unroll
    for (int ks = 0; ks < 2; ++ks)
      qf[u][ks] = *(const bf16x8*)(qkv + (size_t)(b * 2048 + q0 + u * 16 + fr) * 3072 +
                                   h * 64 + ks * 32 + fq * 8);

  bf16x8 ones;
#pragma unroll
  for (int i = 0; i < 8; ++i) ones[i] = (bf16_t)1.0f;

  f32x4 o[2][4] = {};
  f32x4 liacc[2] = {};

  const bf16_t* kg = qkv + (size_t)b * 2048 * 3072 + 1024 + h * 64;  // K[s][d]: kg + s*3072 + d
  const bf16_t* vg = vt + (size_t)(b * 16 + h) * 64 * 2048;          // Vt[d][s]: vg + d*2048 + s

  const int ktmax = (q0 + 31) >> 6;  // last key-tile touching this q range

  auto loadK = [&](bf16x8* kf, int kt) {
    const bf16_t* base = kg + (size_t)(kt * 64 + fr) * 3072 + fq * 8;
#pragma unroll
    for (int t = 0; t < 4; ++t) {
      kf[t * 2 + 0] = *(const bf16x8*)(base + (size_t)t * 16 * 3072);
      kf[t * 2 + 1] = *(const bf16x8*)(base + (size_t)t * 16 * 3072 + 32);
    }
  };
  auto loadV = [&](bf16x8* vf, int kt) {
    const bf16_t* base = vg + (size_t)fr * 2048 + kt * 64 + fq * 8;
#pragma unroll
    for (int dt = 0; dt < 4; ++dt) {
      vf[dt * 2 + 0] = *(const bf16x8*)(base + (size_t)dt * 16 * 2048);
      vf[dt * 2 + 1] = *(const bf16x8*)(base + (size_t)dt * 16 * 2048 + 32);
    }
  };
  auto body = [&](const bf16x8* kf, const bf16x8* vf, int kt) {
    f32x4 s[2][4] = {};
#pragma unroll
    for (int t = 0; t < 4; ++t)
#pragma unroll
      for (int ks = 0; ks < 2; ++ks) {
        s[0][t] = __builtin_amdgcn_mfma_f32_16x16x32_bf16(kf[t * 2 + ks], qf[0][ks], s[0][t], 0, 0, 0);
        s[1][t] = __builtin_amdgcn_mfma_f32_16x16x32_bf16(kf[t * 2 + ks], qf[1][ks], s[1][t], 0, 0, 0);
      }
    const int kbase = kt * 64;
#pragma unroll
    for (int u = 0; u < 2; ++u) {
      const int qq = q0 + u * 16 + fr;
      const bool needmask = (kbase + 63) > (q0 + u * 16);
#pragma unroll
      for (int t = 0; t < 4; ++t) {
        bf16x4 pk;
#pragma unroll
        for (int r = 0; r < 4; ++r) {
          float v = fmaf(s[u][t][r], SCALE_LOG2E, -FIXED_MAX);
          if (needmask && (kbase + t * 16 + fq * 4 + r > qq)) v = -1e30f;
          pk[r] = (bf16_t)__builtin_amdgcn_exp2f(v);
        }
        *(bf16x4*)&lP[w][(u * 16 + fr) * 72 + t * 16 + fq * 4] = pk;
      }
    }
    bf16x8 pf[2][2];
#pragma unroll
    for (int u = 0; u < 2; ++u)
#pragma unroll
      for (int g = 0; g < 2; ++g)
        pf[u][g] = *(const bf16x8*)&lP[w][(u * 16 + fr) * 72 + g * 32 + fq * 8];
#pragma unroll
    for (int g = 0; g < 2; ++g) {
#pragma unroll
      for (int dt = 0; dt < 4; ++dt) {
        o[0][dt] = __builtin_amdgcn_mfma_f32_16x16x32_bf16(vf[dt * 2 + g], pf[0][g], o[0][dt], 0, 0, 0);
        o[1][dt] = __builtin_amdgcn_mfma_f32_16x16x32_bf16(vf[dt * 2 + g], pf[1][g], o[1][dt], 0, 0, 0);
      }
      liacc[0] = __builtin_amdgcn_mfma_f32_16x16x32_bf16(ones, pf[0][g], liacc[0], 0, 0, 0);
      liacc[1] = __builtin_amdgcn_mfma_f32_16x16x32_bf16(ones, pf[1][g], liacc[1], 0, 0, 0);
    }
  };

  if (w <= ktmax) {
    bf16x8 kfa[8], kfb[8], vf[8];
    int kt = w;
    loadK(kfa, kt);
    while (true) {
      loadV(vf, kt);
      loadK(kfb, (kt + 4 <= ktmax) ? kt + 4 : kt);
      body(kfa, vf, kt);
      kt += 4;
      if (kt > ktmax) break;
      loadV(vf, kt);
      loadK(kfa, (kt + 4 <= ktmax) ? kt + 4 : kt);
      body(kfb, vf, kt);
      kt += 4;
      if (kt > ktmax) break;
    }
  }

  // cross-wave reduction of O^T and li
#pragma unroll
  for (int u = 0; u < 2; ++u) {
    if (fq == 0) lRed[w][u * 16 + fr][64] = liacc[u][0];
#pragma unroll
    for (int dt = 0; dt < 4; ++dt)
      *(f32x4*)&lRed[w][u * 16 + fr][dt * 16 + fq * 4] = o[u][dt];
  }
  __syncthreads();
#pragma unroll
  for (int u = 0; u < 2; ++u) {
    const int qr = u * 16 + fr;
    const float lsum = lRed[0][qr][64] + lRed[1][qr][64] + lRed[2][qr][64] + lRed[3][qr][64];
    const float inv = 1.f / lsum;
    bf16_t* cb = ctx + (size_t)(b * 2048 + q0 + qr) * 1024 + h * 64;
#pragma unroll
    for (int dt = 0; dt < 4; ++dt) {
      f32x4 v = *(f32x4*)&lRed[0][qr][dt * 16 + fq * 4];
      v += *(f32x4*)&lRed[1][qr][dt * 16 + fq * 4];
      v += *(f32x4*)&lRed[2][qr][dt * 16 + fq * 4];
      v += *(f32x4*)&lRed[3][qr][dt * 16 + fq * 4];
      bf16x4 ov;
#pragma unroll
      for (int r = 0; r < 4; ++r) ov[r] = (bf16_t)(v[r] * inv);
      *(bf16x4*)(cb + dt * 16 + fq * 4) = ov;
    }
  }
}

extern "C" void kernel_launch(void* const* d_in, const int* in_sizes, int n_in,
                              void* d_out, int out_size, void* d_ws, size_t ws_size,
                              hipStream_t stream) {
  const float* x  = (const float*)d_in[0];
  const float* q  = (const float*)d_in[1];
  const float* WQ = (const float*)d_in[2];
  const float* WK = (const float*)d_in[3];
  const float* WV = (const float*)d_in[4];
  const float* WO = (const float*)d_in[5];
  float* out = (float*)d_out;

  bf16_t* qb  = (bf16_t*)d_ws;
  bf16_t* xb  = qb + 4194304;
  bf16_t* wt  = xb + 4194304;
  bf16_t* qkv = wt + 4194304;
  bf16_t* vtp = qkv + (size_t)4096 * 3072;
  bf16_t* ctx = vtp + 4194304;

  prep<<<dim3(5120), 256, 0, stream>>>(x, q, WQ, WK, WV, WO, xb, qb, wt);
  gemm128<0><<<dim3(24, 32), 256, 0, stream>>>(qb, xb, wt, qkv, vtp, nullptr);
  attn32<<<dim3(32, 64), 256, 0, stream>>>(qkv, vtp, ctx);
  gemm128<2><<<dim3(16, 32), 256, 0, stream>>>(ctx, ctx, wt + (size_t)3072 * 1024,
                                               nullptr, nullptr, out);
}

// Round 6
// 193.646 us; speedup vs baseline: 1.1808x; 1.1808x over previous
//
#include <hip/hip_runtime.h>

// Shapes (fixed): B=2, S=2048, D=1024, H=16, hd=64. M = B*S = 4096.
// ws layout (bf16 elems): qb[4M] | xb[4M] | wt[4M] | qkv[4096*3072] | vt[2][16][64][2048] | ctx[4M]

typedef __bf16 bf16_t;
typedef __attribute__((ext_vector_type(8))) __bf16 bf16x8;
typedef __attribute__((ext_vector_type(4))) __bf16 bf16x4;
typedef __attribute__((ext_vector_type(4))) float f32x4;

#define SCALE_LOG2E 0.045084220027780106f  // log2(e)/32
#define FIXED_MAX 8.0f

__device__ __forceinline__ void async_load16(const void* g, void* l) {
  __builtin_amdgcn_global_load_lds(
      (const __attribute__((address_space(1))) void*)g,
      (__attribute__((address_space(3))) void*)l, 16, 0, 0);
}

// ---- fused prep: blocks 0..4095 cast x/q_in; blocks 4096..5119 cast+transpose weights ----
__global__ void prep(const float* __restrict__ x, const float* __restrict__ q,
                     const float* __restrict__ w0, const float* __restrict__ w1,
                     const float* __restrict__ w2, const float* __restrict__ w3,
                     bf16_t* __restrict__ xb, bf16_t* __restrict__ qb,
                     bf16_t* __restrict__ wt) {
  const int bid = blockIdx.x;
  if (bid < 4096) {
    const float* src = (bid >= 2048) ? q : x;
    bf16_t* dst = (bid >= 2048) ? qb : xb;
    const size_t i = ((size_t)(bid & 2047) * 256 + threadIdx.x) * 8;
    float4 v0 = *(const float4*)(src + i);
    float4 v1 = *(const float4*)(src + i + 4);
    bf16x8 o;
    o[0] = (bf16_t)v0.x; o[1] = (bf16_t)v0.y; o[2] = (bf16_t)v0.z; o[3] = (bf16_t)v0.w;
    o[4] = (bf16_t)v1.x; o[5] = (bf16_t)v1.y; o[6] = (bf16_t)v1.z; o[7] = (bf16_t)v1.w;
    *(bf16x8*)(dst + i) = o;
  } else {
    const int wb = bid - 4096;
    const int z = wb >> 8;
    const float* W = z == 0 ? w0 : z == 1 ? w1 : z == 2 ? w2 : w3;
    bf16_t* dst = wt + (size_t)z * 1048576;
    const int r0 = ((wb >> 4) & 15) * 64, c0 = (wb & 15) * 64;
    __shared__ bf16_t t[64][72];
#pragma unroll
    for (int i = 0; i < 16; ++i) {
      int flat = i * 256 + threadIdx.x;
      int r = flat >> 6, c = flat & 63;
      t[c][r] = (bf16_t)W[(size_t)(r0 + r) * 1024 + c0 + c];
    }
    __syncthreads();
    const int c = threadIdx.x >> 2, seg = (threadIdx.x & 3) * 16;
    bf16x8 a = *(const bf16x8*)&t[c][seg];
    bf16x8 b = *(const bf16x8*)&t[c][seg + 8];
    bf16_t* drow = dst + (size_t)(c0 + c) * 1024 + r0 + seg;
    *(bf16x8*)drow = a;
    *(bf16x8*)(drow + 8) = b;
  }
}

// ---- GEMM (m97-style, BK=32). MODE 0: fused QKV 128x128. MODE 2: out GEMM 128x64, fp32. ----
template <int MODE>
__global__ __launch_bounds__(256, MODE == 2 ? 4 : 2) void gemm128(
    const bf16_t* __restrict__ Aq, const bf16_t* __restrict__ Ax,
    const bf16_t* __restrict__ Bt,
    bf16_t* __restrict__ Cq, bf16_t* __restrict__ Cvt, float* __restrict__ Cf) {
  constexpr int K = 1024;
  constexpr int NT = (MODE == 2) ? 2 : 4;
  constexpr int NROWS = NT * 32;
  const int n0 = blockIdx.x * NROWS;
  const int m0 = blockIdx.y * 128;
  const bf16_t* A = (MODE == 0 && n0 >= 1024) ? Ax : Aq;

  __shared__ bf16_t lA[128 * 32];
  __shared__ bf16_t lB[NROWS * 32];

  const int tid = threadIdx.x;
  const int w = tid >> 6, l = tid & 63;
  const int wm = (w & 1) * 64, wn = (w >> 1) * (NT * 16);
  const int sr = l >> 2;
  const int sk = (l & 3) * 8;
  const int fr = l & 15, fc = (l >> 4) * 8;

  f32x4 acc[4][NT] = {};

  for (int kt = 0; kt < K; kt += 32) {
    __syncthreads();
#pragma unroll
    for (int c = 0; c < 2; ++c) {
      const int ch = w * 2 + c;
      async_load16(A + (size_t)(m0 + ch * 16 + sr) * K + kt + sk, &lA[ch * 512]);
      if (NT == 4 || c == 0) {
        const int bch = (NT == 4) ? ch : w;
        async_load16(Bt + (size_t)(n0 + bch * 16 + sr) * K + kt + sk, &lB[bch * 512]);
      }
    }
    __syncthreads();
    bf16x8 af[4], bfr[NT];
#pragma unroll
    for (int i = 0; i < 4; ++i) af[i] = *(const bf16x8*)&lA[(wm + i * 16 + fr) * 32 + fc];
#pragma unroll
    for (int j = 0; j < NT; ++j) bfr[j] = *(const bf16x8*)&lB[(wn + j * 16 + fr) * 32 + fc];
#pragma unroll
    for (int i = 0; i < 4; ++i)
#pragma unroll
      for (int j = 0; j < NT; ++j)
        acc[i][j] = __builtin_amdgcn_mfma_f32_16x16x32_bf16(af[i], bfr[j], acc[i][j], 0, 0, 0);
  }

  if (MODE == 2) {
#pragma unroll
    for (int i = 0; i < 4; ++i) {
      const int m = m0 + wm + i * 16 + (l >> 4) * 4;
#pragma unroll
      for (int j = 0; j < NT; ++j) {
        const int n = n0 + wn + j * 16 + fr;
#pragma unroll
        for (int r = 0; r < 4; ++r) Cf[(size_t)(m + r) * 1024 + n] = acc[i][j][r];
      }
    }
  } else if (n0 < 2048) {
#pragma unroll
    for (int i = 0; i < 4; ++i) {
      const int m = m0 + wm + i * 16 + (l >> 4) * 4;
#pragma unroll
      for (int j = 0; j < NT; ++j) {
        const int n = n0 + wn + j * 16 + fr;
#pragma unroll
        for (int r = 0; r < 4; ++r) Cq[(size_t)(m + r) * 3072 + n] = (bf16_t)acc[i][j][r];
      }
    }
  } else {
#pragma unroll
    for (int i = 0; i < 4; ++i) {
      const int mb = m0 + wm + i * 16 + (l >> 4) * 4;
      const int bb = mb >> 11, ss = mb & 2047;
#pragma unroll
      for (int j = 0; j < NT; ++j) {
        const int nn = n0 - 2048 + wn + j * 16 + fr;
        const int hh = nn >> 6, dd = nn & 63;
        bf16x4 pk;
#pragma unroll
        for (int r = 0; r < 4; ++r) pk[r] = (bf16_t)acc[i][j][r];
        *(bf16x4*)(Cvt + (size_t)((bb * 16 + hh) * 64 + dd) * 2048 + ss) = pk;
      }
    }
  }
}

// ---- flash attention v4: uniform paired 64-q tiles, 2 blocks/CU, 8 waves/CU throughout ----
// Block (bh, p) processes q-tile 16+p then q-tile 15-p sequentially: (17+p)+(16-p)=33 iters
// for EVERY block -> zero tail, full concurrency. Wave owns 16 q. S^T=K·Q^T formulation,
// fixed-max softmax, per-wave P^T LDS round-trip, li via ones-MFMA, K/V dbuf XOR-swizzled.
__global__ __launch_bounds__(256, 2) void attn64p(const bf16_t* __restrict__ qkv,
                                                  const bf16_t* __restrict__ vt,
                                                  bf16_t* __restrict__ ctx) {
  const int p = blockIdx.y;       // 0..15
  const int bh = blockIdx.x;
  const int b = bh >> 4, h = bh & 15;
  const int tid = threadIdx.x, w = tid >> 6, l = tid & 63;
  const int fr = l & 15, fq = l >> 4;

  __shared__ __align__(16) bf16_t lK[2][64 * 64];
  __shared__ __align__(16) bf16_t lV[2][64 * 64];
  __shared__ __align__(16) bf16_t lP[4][16 * 72];

  const bf16_t* kg = qkv + (size_t)b * 2048 * 3072 + 1024 + h * 64;
  const bf16_t* vg = vt + (size_t)(b * 16 + h) * 64 * 2048;

  const int srow = l >> 3;
  const int swz = ((l & 7) ^ srow) * 8;
  const int xr = fr & 7;

  bf16x8 ones;
#pragma unroll
  for (int i = 0; i < 8; ++i) ones[i] = (bf16_t)1.0f;

#pragma unroll 1
  for (int phase = 0; phase < 2; ++phase) {
    const int qt = (phase == 0) ? (16 + p) : (15 - p);
    const int q0 = qt * 64;
    const int qw = q0 + w * 16;   // this wave's q base
    const int ktmax = qt;

    bf16x8 qf[2];
#pragma unroll
    for (int ks = 0; ks < 2; ++ks)
      qf[ks] = *(const bf16x8*)(qkv + (size_t)(b * 2048 + qw + fr) * 3072 +
                                h * 64 + ks * 32 + fq * 8);

    f32x4 o[4] = {};
    f32x4 liacc = {};

    if (phase == 1) __syncthreads();  // protect LDS buf reuse across phases
#pragma unroll
    for (int c = 0; c < 2; ++c) {
      const int row = w * 16 + c * 8 + srow;
      async_load16(kg + (size_t)row * 3072 + swz, &lK[0][(w * 16 + c * 8) * 64]);
      async_load16(vg + (size_t)row * 2048 + swz, &lV[0][(w * 16 + c * 8) * 64]);
    }

    for (int kt = 0; kt <= ktmax; ++kt) {
      const int buf = kt & 1;
      __syncthreads();
      if (kt < ktmax) {
#pragma unroll
        for (int c = 0; c < 2; ++c) {
          const int row = w * 16 + c * 8 + srow;
          async_load16(kg + (size_t)((kt + 1) * 64 + row) * 3072 + swz,
                       &lK[buf ^ 1][(w * 16 + c * 8) * 64]);
          async_load16(vg + (size_t)row * 2048 + (kt + 1) * 64 + swz,
                       &lV[buf ^ 1][(w * 16 + c * 8) * 64]);
        }
      }

      // S^T[key][q] = K·Q^T
      f32x4 s[4] = {};
#pragma unroll
      for (int t = 0; t < 4; ++t)
#pragma unroll
        for (int ks = 0; ks < 2; ++ks) {
          bf16x8 kf = *(const bf16x8*)&lK[buf][(t * 16 + fr) * 64 + ((ks * 4 + fq) ^ xr) * 8];
          s[t] = __builtin_amdgcn_mfma_f32_16x16x32_bf16(kf, qf[ks], s[t], 0, 0, 0);
        }

      const int kbase = kt * 64;
      const int qq = qw + fr;
      const bool needmask = (kbase + 63) > qw;
#pragma unroll
      for (int t = 0; t < 4; ++t) {
        bf16x4 pk;
#pragma unroll
        for (int r = 0; r < 4; ++r) {
          float v = fmaf(s[t][r], SCALE_LOG2E, -FIXED_MAX);
          if (needmask && (kbase + t * 16 + fq * 4 + r > qq)) v = -1e30f;
          pk[r] = (bf16_t)__builtin_amdgcn_exp2f(v);
        }
        *(bf16x4*)&lP[w][fr * 72 + t * 16 + fq * 4] = pk;
      }

      // O^T += V^T·P ; li += ones·P  (per-wave lP: in-wave lgkm ordering, no barrier)
      bf16x8 pf[2];
#pragma unroll
      for (int g = 0; g < 2; ++g)
        pf[g] = *(const bf16x8*)&lP[w][fr * 72 + g * 32 + fq * 8];
#pragma unroll
      for (int g = 0; g < 2; ++g) {
#pragma unroll
        for (int dt = 0; dt < 4; ++dt) {
          bf16x8 vf = *(const bf16x8*)&lV[buf][(dt * 16 + fr) * 64 + ((g * 4 + fq) ^ xr) * 8];
          o[dt] = __builtin_amdgcn_mfma_f32_16x16x32_bf16(vf, pf[g], o[dt], 0, 0, 0);
        }
        liacc = __builtin_amdgcn_mfma_f32_16x16x32_bf16(ones, pf[g], liacc, 0, 0, 0);
      }
    }

    // epilogue: li complete per lane (C-layout col = fr = q); normalize & store
    const float inv = 1.f / liacc[0];
    bf16_t* cb = ctx + (size_t)(b * 2048 + qw + fr) * 1024 + h * 64;
#pragma unroll
    for (int dt = 0; dt < 4; ++dt) {
      bf16x4 ov;
#pragma unroll
      for (int r = 0; r < 4; ++r) ov[r] = (bf16_t)(o[dt][r] * inv);
      *(bf16x4*)(cb + dt * 16 + fq * 4) = ov;
    }
  }
}

extern "C" void kernel_launch(void* const* d_in, const int* in_sizes, int n_in,
                              void* d_out, int out_size, void* d_ws, size_t ws_size,
                              hipStream_t stream) {
  const float* x  = (const float*)d_in[0];
  const float* q  = (const float*)d_in[1];
  const float* WQ = (const float*)d_in[2];
  const float* WK = (const float*)d_in[3];
  const float* WV = (const float*)d_in[4];
  const float* WO = (const float*)d_in[5];
  float* out = (float*)d_out;

  bf16_t* qb  = (bf16_t*)d_ws;
  bf16_t* xb  = qb + 4194304;
  bf16_t* wt  = xb + 4194304;
  bf16_t* qkv = wt + 4194304;
  bf16_t* vtp = qkv + (size_t)4096 * 3072;
  bf16_t* ctx = vtp + 4194304;

  prep<<<dim3(5120), 256, 0, stream>>>(x, q, WQ, WK, WV, WO, xb, qb, wt);
  gemm128<0><<<dim3(24, 32), 256, 0, stream>>>(qb, xb, wt, qkv, vtp, nullptr);
  attn64p<<<dim3(32, 16), 256, 0, stream>>>(qkv, vtp, ctx);
  gemm128<2><<<dim3(16, 32), 256, 0, stream>>>(ctx, ctx, wt + (size_t)3072 * 1024,
                                               nullptr, nullptr, out);
}

// Round 7
// 193.075 us; speedup vs baseline: 1.1843x; 1.0030x over previous
//
#include <hip/hip_runtime.h>

// Shapes (fixed): B=2, S=2048, D=1024, H=16, hd=64. M = B*S = 4096.
// ws layout (bf16 elems): qb[4M] | xb[4M] | wt[4M] | qkv[4096*3072] | vt[2][16][64][2048] | ctx[4M]

typedef __bf16 bf16_t;
typedef __attribute__((ext_vector_type(8))) __bf16 bf16x8;
typedef __attribute__((ext_vector_type(4))) __bf16 bf16x4;
typedef __attribute__((ext_vector_type(4))) float f32x4;

#define SCALE_LOG2E 0.045084220027780106f  // log2(e)/32
#define FIXED_MAX 8.0f

__device__ __forceinline__ void async_load16(const void* g, void* l) {
  __builtin_amdgcn_global_load_lds(
      (const __attribute__((address_space(1))) void*)g,
      (__attribute__((address_space(3))) void*)l, 16, 0, 0);
}

// ---- fused prep: blocks 0..4095 cast x/q_in; blocks 4096..5119 cast+transpose weights ----
__global__ void prep(const float* __restrict__ x, const float* __restrict__ q,
                     const float* __restrict__ w0, const float* __restrict__ w1,
                     const float* __restrict__ w2, const float* __restrict__ w3,
                     bf16_t* __restrict__ xb, bf16_t* __restrict__ qb,
                     bf16_t* __restrict__ wt) {
  const int bid = blockIdx.x;
  if (bid < 4096) {
    const float* src = (bid >= 2048) ? q : x;
    bf16_t* dst = (bid >= 2048) ? qb : xb;
    const size_t i = ((size_t)(bid & 2047) * 256 + threadIdx.x) * 8;
    float4 v0 = *(const float4*)(src + i);
    float4 v1 = *(const float4*)(src + i + 4);
    bf16x8 o;
    o[0] = (bf16_t)v0.x; o[1] = (bf16_t)v0.y; o[2] = (bf16_t)v0.z; o[3] = (bf16_t)v0.w;
    o[4] = (bf16_t)v1.x; o[5] = (bf16_t)v1.y; o[6] = (bf16_t)v1.z; o[7] = (bf16_t)v1.w;
    *(bf16x8*)(dst + i) = o;
  } else {
    const int wb = bid - 4096;
    const int z = wb >> 8;
    const float* W = z == 0 ? w0 : z == 1 ? w1 : z == 2 ? w2 : w3;
    bf16_t* dst = wt + (size_t)z * 1048576;
    const int r0 = ((wb >> 4) & 15) * 64, c0 = (wb & 15) * 64;
    __shared__ bf16_t t[64][72];
#pragma unroll
    for (int i = 0; i < 16; ++i) {
      int flat = i * 256 + threadIdx.x;
      int r = flat >> 6, c = flat & 63;
      t[c][r] = (bf16_t)W[(size_t)(r0 + r) * 1024 + c0 + c];
    }
    __syncthreads();
    const int c = threadIdx.x >> 2, seg = (threadIdx.x & 3) * 16;
    bf16x8 a = *(const bf16x8*)&t[c][seg];
    bf16x8 b = *(const bf16x8*)&t[c][seg + 8];
    bf16_t* drow = dst + (size_t)(c0 + c) * 1024 + r0 + seg;
    *(bf16x8*)drow = a;
    *(bf16x8*)(drow + 8) = b;
  }
}

// ---- GEMM (m97-style, BK=32). MODE 0: fused QKV 128x128. MODE 2: out GEMM 128x64, fp32. ----
template <int MODE>
__global__ __launch_bounds__(256, MODE == 2 ? 4 : 2) void gemm128(
    const bf16_t* __restrict__ Aq, const bf16_t* __restrict__ Ax,
    const bf16_t* __restrict__ Bt,
    bf16_t* __restrict__ Cq, bf16_t* __restrict__ Cvt, float* __restrict__ Cf) {
  constexpr int K = 1024;
  constexpr int NT = (MODE == 2) ? 2 : 4;
  constexpr int NROWS = NT * 32;
  const int n0 = blockIdx.x * NROWS;
  const int m0 = blockIdx.y * 128;
  const bf16_t* A = (MODE == 0 && n0 >= 1024) ? Ax : Aq;

  __shared__ bf16_t lA[128 * 32];
  __shared__ bf16_t lB[NROWS * 32];

  const int tid = threadIdx.x;
  const int w = tid >> 6, l = tid & 63;
  const int wm = (w & 1) * 64, wn = (w >> 1) * (NT * 16);
  const int sr = l >> 2;
  const int sk = (l & 3) * 8;
  const int fr = l & 15, fc = (l >> 4) * 8;

  f32x4 acc[4][NT] = {};

  for (int kt = 0; kt < K; kt += 32) {
    __syncthreads();
#pragma unroll
    for (int c = 0; c < 2; ++c) {
      const int ch = w * 2 + c;
      async_load16(A + (size_t)(m0 + ch * 16 + sr) * K + kt + sk, &lA[ch * 512]);
      if (NT == 4 || c == 0) {
        const int bch = (NT == 4) ? ch : w;
        async_load16(Bt + (size_t)(n0 + bch * 16 + sr) * K + kt + sk, &lB[bch * 512]);
      }
    }
    __syncthreads();
    bf16x8 af[4], bfr[NT];
#pragma unroll
    for (int i = 0; i < 4; ++i) af[i] = *(const bf16x8*)&lA[(wm + i * 16 + fr) * 32 + fc];
#pragma unroll
    for (int j = 0; j < NT; ++j) bfr[j] = *(const bf16x8*)&lB[(wn + j * 16 + fr) * 32 + fc];
#pragma unroll
    for (int i = 0; i < 4; ++i)
#pragma unroll
      for (int j = 0; j < NT; ++j)
        acc[i][j] = __builtin_amdgcn_mfma_f32_16x16x32_bf16(af[i], bfr[j], acc[i][j], 0, 0, 0);
  }

  if (MODE == 2) {
#pragma unroll
    for (int i = 0; i < 4; ++i) {
      const int m = m0 + wm + i * 16 + (l >> 4) * 4;
#pragma unroll
      for (int j = 0; j < NT; ++j) {
        const int n = n0 + wn + j * 16 + fr;
#pragma unroll
        for (int r = 0; r < 4; ++r) Cf[(size_t)(m + r) * 1024 + n] = acc[i][j][r];
      }
    }
  } else if (n0 < 2048) {
#pragma unroll
    for (int i = 0; i < 4; ++i) {
      const int m = m0 + wm + i * 16 + (l >> 4) * 4;
#pragma unroll
      for (int j = 0; j < NT; ++j) {
        const int n = n0 + wn + j * 16 + fr;
#pragma unroll
        for (int r = 0; r < 4; ++r) Cq[(size_t)(m + r) * 3072 + n] = (bf16_t)acc[i][j][r];
      }
    }
  } else {
#pragma unroll
    for (int i = 0; i < 4; ++i) {
      const int mb = m0 + wm + i * 16 + (l >> 4) * 4;
      const int bb = mb >> 11, ss = mb & 2047;
#pragma unroll
      for (int j = 0; j < NT; ++j) {
        const int nn = n0 - 2048 + wn + j * 16 + fr;
        const int hh = nn >> 6, dd = nn & 63;
        bf16x4 pk;
#pragma unroll
        for (int r = 0; r < 4; ++r) pk[r] = (bf16_t)acc[i][j][r];
        *(bf16x4*)(Cvt + (size_t)((bb * 16 + hh) * 64 + dd) * 2048 + ss) = pk;
      }
    }
  }
}

// ---- flash attention v5: uniform paired 64-q blocks; waves split (q-half x key-half) ----
// Each wave: 32 q x 32 keys per tile -> K/V LDS reads amortize 2x vs v4 (12 KB vs 20 KB
// per 1024 scores). Key-half partners (w, w^2) reduce partial O^T/li via LDS per phase.
// lP XOR-swizzled (conflict-free b128 reads). Diagonal upper-key wave skips compute.
__global__ __launch_bounds__(256, 2) void attn64k(const bf16_t* __restrict__ qkv,
                                                  const bf16_t* __restrict__ vt,
                                                  bf16_t* __restrict__ ctx) {
  const int p = blockIdx.y;       // 0..15
  const int bh = blockIdx.x;
  const int b = bh >> 4, h = bh & 15;
  const int tid = threadIdx.x, w = tid >> 6, l = tid & 63;
  const int fr = l & 15, fq = l >> 4;
  const int qhalf = w & 1, khalf = w >> 1;

  __shared__ __align__(16) bf16_t lK[2][64 * 64];   // 16 KB
  __shared__ __align__(16) bf16_t lV[2][64 * 64];   // 16 KB
  __shared__ __align__(16) bf16_t lP[4][32 * 32];   // 8 KB, XOR-swizzled 8-elem groups
  __shared__ __align__(16) float lRed[2][32][68];   // 17.4 KB partial O^T + li

  const bf16_t* kg = qkv + (size_t)b * 2048 * 3072 + 1024 + h * 64;
  const bf16_t* vg = vt + (size_t)(b * 16 + h) * 64 * 2048;

  const int srow = l >> 3;
  const int swz = ((l & 7) ^ srow) * 8;
  const int xr = fr & 7;
  const int fr3 = fr & 3;

  bf16x8 ones;
#pragma unroll
  for (int i = 0; i < 8; ++i) ones[i] = (bf16_t)1.0f;

#pragma unroll 1
  for (int phase = 0; phase < 2; ++phase) {
    const int qt = (phase == 0) ? (16 + p) : (15 - p);
    const int q0 = qt * 64;
    const int qw = q0 + qhalf * 32;   // this wave's 32-q base

    bf16x8 qf[2][2];
#pragma unroll
    for (int u = 0; u < 2; ++u)
#pragma unroll
      for (int ks = 0; ks < 2; ++ks)
        qf[u][ks] = *(const bf16x8*)(qkv + (size_t)(b * 2048 + qw + u * 16 + fr) * 3072 +
                                     h * 64 + ks * 32 + fq * 8);

    f32x4 o[2][4] = {};
    f32x4 liacc[2] = {};

    if (phase == 1) __syncthreads();  // protect LDS reuse across phases
#pragma unroll
    for (int c = 0; c < 2; ++c) {
      const int row = w * 16 + c * 8 + srow;
      async_load16(kg + (size_t)row * 3072 + swz, &lK[0][(w * 16 + c * 8) * 64]);
      async_load16(vg + (size_t)row * 2048 + swz, &lV[0][(w * 16 + c * 8) * 64]);
    }

    for (int kt = 0; kt <= qt; ++kt) {
      const int buf = kt & 1;
      __syncthreads();
      if (kt < qt) {
#pragma unroll
        for (int c = 0; c < 2; ++c) {
          const int row = w * 16 + c * 8 + srow;
          async_load16(kg + (size_t)((kt + 1) * 64 + row) * 3072 + swz,
                       &lK[buf ^ 1][(w * 16 + c * 8) * 64]);
          async_load16(vg + (size_t)row * 2048 + (kt + 1) * 64 + swz,
                       &lV[buf ^ 1][(w * 16 + c * 8) * 64]);
        }
      }

      const int kb = kt * 64 + khalf * 32;   // wave's global key base
      if (kb > qw + 31) continue;            // wave fully masked (diagonal upper half)

      // S^T[key][q] = K·Q^T over 32 keys x 32 q
      f32x4 s[2][2] = {};
#pragma unroll
      for (int t = 0; t < 2; ++t)
#pragma unroll
        for (int ks = 0; ks < 2; ++ks) {
          bf16x8 kf = *(const bf16x8*)&lK[buf][(khalf * 32 + t * 16 + fr) * 64 +
                                              ((ks * 4 + fq) ^ xr) * 8];
          s[0][t] = __builtin_amdgcn_mfma_f32_16x16x32_bf16(kf, qf[0][ks], s[0][t], 0, 0, 0);
          s[1][t] = __builtin_amdgcn_mfma_f32_16x16x32_bf16(kf, qf[1][ks], s[1][t], 0, 0, 0);
        }

#pragma unroll
      for (int u = 0; u < 2; ++u) {
        const int qq = qw + u * 16 + fr;
        const bool needmask = (kb + 31) > (qw + u * 16);
#pragma unroll
        for (int t = 0; t < 2; ++t) {
          bf16x4 pk;
#pragma unroll
          for (int r = 0; r < 4; ++r) {
            float v = fmaf(s[u][t][r], SCALE_LOG2E, -FIXED_MAX);
            if (needmask && (kb + t * 16 + fq * 4 + r > qq)) v = -1e30f;
            pk[r] = (bf16_t)__builtin_amdgcn_exp2f(v);
          }
          // q-major row u*16+fr; logical col-group (2t + fq/2) XOR-swizzled by row&3
          const int gs = (2 * t + (fq >> 1)) ^ fr3;
          *(bf16x4*)&lP[w][(u * 16 + fr) * 32 + gs * 8 + (fq & 1) * 4] = pk;
        }
      }

      // O^T += V^T·P ; li += ones·P  (per-wave lP: in-wave lgkm ordering, no barrier)
      bf16x8 pf[2];
#pragma unroll
      for (int u = 0; u < 2; ++u)
        pf[u] = *(const bf16x8*)&lP[w][(u * 16 + fr) * 32 + (fq ^ fr3) * 8];
#pragma unroll
      for (int dt = 0; dt < 4; ++dt) {
        bf16x8 vf = *(const bf16x8*)&lV[buf][(dt * 16 + fr) * 64 +
                                            ((khalf * 4 + fq) ^ xr) * 8];
        o[0][dt] = __builtin_amdgcn_mfma_f32_16x16x32_bf16(vf, pf[0], o[0][dt], 0, 0, 0);
        o[1][dt] = __builtin_amdgcn_mfma_f32_16x16x32_bf16(vf, pf[1], o[1][dt], 0, 0, 0);
      }
      liacc[0] = __builtin_amdgcn_mfma_f32_16x16x32_bf16(ones, pf[0], liacc[0], 0, 0, 0);
      liacc[1] = __builtin_amdgcn_mfma_f32_16x16x32_bf16(ones, pf[1], liacc[1], 0, 0, 0);
    }

    // key-half reduction: khalf=1 writes partials, khalf=0 adds + stores
    __syncthreads();
    if (khalf) {
#pragma unroll
      for (int u = 0; u < 2; ++u) {
#pragma unroll
        for (int dt = 0; dt < 4; ++dt)
          *(f32x4*)&lRed[qhalf][u * 16 + fr][dt * 16 + fq * 4] = o[u][dt];
        if (fq == 0) lRed[qhalf][u * 16 + fr][64] = liacc[u][0];
      }
    }
    __syncthreads();
    if (!khalf) {
#pragma unroll
      for (int u = 0; u < 2; ++u) {
        const float lsum = liacc[u][0] + lRed[qhalf][u * 16 + fr][64];
        const float inv = 1.f / lsum;
        bf16_t* cb = ctx + (size_t)(b * 2048 + qw + u * 16 + fr) * 1024 + h * 64;
#pragma unroll
        for (int dt = 0; dt < 4; ++dt) {
          f32x4 v = o[u][dt] + *(f32x4*)&lRed[qhalf][u * 16 + fr][dt * 16 + fq * 4];
          bf16x4 ov;
#pragma unroll
          for (int r = 0; r < 4; ++r) ov[r] = (bf16_t)(v[r] * inv);
          *(bf16x4*)(cb + dt * 16 + fq * 4) = ov;
        }
      }
    }
  }
}

extern "C" void kernel_launch(void* const* d_in, const int* in_sizes, int n_in,
                              void* d_out, int out_size, void* d_ws, size_t ws_size,
                              hipStream_t stream) {
  const float* x  = (const float*)d_in[0];
  const float* q  = (const float*)d_in[1];
  const float* WQ = (const float*)d_in[2];
  const float* WK = (const float*)d_in[3];
  const float* WV = (const float*)d_in[4];
  const float* WO = (const float*)d_in[5];
  float* out = (float*)d_out;

  bf16_t* qb  = (bf16_t*)d_ws;
  bf16_t* xb  = qb + 4194304;
  bf16_t* wt  = xb + 4194304;
  bf16_t* qkv = wt + 4194304;
  bf16_t* vtp = qkv + (size_t)4096 * 3072;
  bf16_t* ctx = vtp + 4194304;

  prep<<<dim3(5120), 256, 0, stream>>>(x, q, WQ, WK, WV, WO, xb, qb, wt);
  gemm128<0><<<dim3(24, 32), 256, 0, stream>>>(qb, xb, wt, qkv, vtp, nullptr);
  attn64k<<<dim3(32, 16), 256, 0, stream>>>(qkv, vtp, ctx);
  gemm128<2><<<dim3(16, 32), 256, 0, stream>>>(ctx, ctx, wt + (size_t)3072 * 1024,
                                               nullptr, nullptr, out);
}

// Round 8
// 188.298 us; speedup vs baseline: 1.2144x; 1.0254x over previous
//
#include <hip/hip_runtime.h>

// Shapes (fixed): B=2, S=2048, D=1024, H=16, hd=64. M = B*S = 4096.
// ws layout (bf16 elems): qb[4M] | xb[4M] | wt[4M] | qkv[4096*3072] | vt[2][16][64][2048] | ctx[4M]

typedef __bf16 bf16_t;
typedef __attribute__((ext_vector_type(8))) __bf16 bf16x8;
typedef __attribute__((ext_vector_type(4))) __bf16 bf16x4;
typedef __attribute__((ext_vector_type(4))) float f32x4;

#define SCALE_LOG2E 0.045084220027780106f  // log2(e)/32
#define FIXED_MAX 8.0f

__device__ __forceinline__ void async_load16(const void* g, void* l) {
  __builtin_amdgcn_global_load_lds(
      (const __attribute__((address_space(1))) void*)g,
      (__attribute__((address_space(3))) void*)l, 16, 0, 0);
}

// ---- fused prep: blocks 0..4095 cast x/q_in; blocks 4096..5119 cast+transpose weights ----
__global__ void prep(const float* __restrict__ x, const float* __restrict__ q,
                     const float* __restrict__ w0, const float* __restrict__ w1,
                     const float* __restrict__ w2, const float* __restrict__ w3,
                     bf16_t* __restrict__ xb, bf16_t* __restrict__ qb,
                     bf16_t* __restrict__ wt) {
  const int bid = blockIdx.x;
  if (bid < 4096) {
    const float* src = (bid >= 2048) ? q : x;
    bf16_t* dst = (bid >= 2048) ? qb : xb;
    const size_t i = ((size_t)(bid & 2047) * 256 + threadIdx.x) * 8;
    float4 v0 = *(const float4*)(src + i);
    float4 v1 = *(const float4*)(src + i + 4);
    bf16x8 o;
    o[0] = (bf16_t)v0.x; o[1] = (bf16_t)v0.y; o[2] = (bf16_t)v0.z; o[3] = (bf16_t)v0.w;
    o[4] = (bf16_t)v1.x; o[5] = (bf16_t)v1.y; o[6] = (bf16_t)v1.z; o[7] = (bf16_t)v1.w;
    *(bf16x8*)(dst + i) = o;
  } else {
    const int wb = bid - 4096;
    const int z = wb >> 8;
    const float* W = z == 0 ? w0 : z == 1 ? w1 : z == 2 ? w2 : w3;
    bf16_t* dst = wt + (size_t)z * 1048576;
    const int r0 = ((wb >> 4) & 15) * 64, c0 = (wb & 15) * 64;
    __shared__ bf16_t t[64][72];
#pragma unroll
    for (int i = 0; i < 16; ++i) {
      int flat = i * 256 + threadIdx.x;
      int r = flat >> 6, c = flat & 63;
      t[c][r] = (bf16_t)W[(size_t)(r0 + r) * 1024 + c0 + c];
    }
    __syncthreads();
    const int c = threadIdx.x >> 2, seg = (threadIdx.x & 3) * 16;
    bf16x8 a = *(const bf16x8*)&t[c][seg];
    bf16x8 b = *(const bf16x8*)&t[c][seg + 8];
    bf16_t* drow = dst + (size_t)(c0 + c) * 1024 + r0 + seg;
    *(bf16x8*)drow = a;
    *(bf16x8*)(drow + 8) = b;
  }
}

// ---- GEMM (m97-style, BK=32). MODE 0: fused QKV 128x128 (3 blk/CU). MODE 2: out 128x64 fp32. ----
template <int MODE>
__global__ __launch_bounds__(256, MODE == 2 ? 4 : 3) void gemm128(
    const bf16_t* __restrict__ Aq, const bf16_t* __restrict__ Ax,
    const bf16_t* __restrict__ Bt,
    bf16_t* __restrict__ Cq, bf16_t* __restrict__ Cvt, float* __restrict__ Cf) {
  constexpr int K = 1024;
  constexpr int NT = (MODE == 2) ? 2 : 4;
  constexpr int NROWS = NT * 32;
  const int n0 = blockIdx.x * NROWS;
  const int m0 = blockIdx.y * 128;
  const bf16_t* A = (MODE == 0 && n0 >= 1024) ? Ax : Aq;

  __shared__ bf16_t lA[128 * 32];
  __shared__ bf16_t lB[NROWS * 32];

  const int tid = threadIdx.x;
  const int w = tid >> 6, l = tid & 63;
  const int wm = (w & 1) * 64, wn = (w >> 1) * (NT * 16);
  const int sr = l >> 2;
  const int sk = (l & 3) * 8;
  const int fr = l & 15, fc = (l >> 4) * 8;

  f32x4 acc[4][NT] = {};

  for (int kt = 0; kt < K; kt += 32) {
    __syncthreads();
#pragma unroll
    for (int c = 0; c < 2; ++c) {
      const int ch = w * 2 + c;
      async_load16(A + (size_t)(m0 + ch * 16 + sr) * K + kt + sk, &lA[ch * 512]);
      if (NT == 4 || c == 0) {
        const int bch = (NT == 4) ? ch : w;
        async_load16(Bt + (size_t)(n0 + bch * 16 + sr) * K + kt + sk, &lB[bch * 512]);
      }
    }
    __syncthreads();
    bf16x8 af[4], bfr[NT];
#pragma unroll
    for (int i = 0; i < 4; ++i) af[i] = *(const bf16x8*)&lA[(wm + i * 16 + fr) * 32 + fc];
#pragma unroll
    for (int j = 0; j < NT; ++j) bfr[j] = *(const bf16x8*)&lB[(wn + j * 16 + fr) * 32 + fc];
#pragma unroll
    for (int i = 0; i < 4; ++i)
#pragma unroll
      for (int j = 0; j < NT; ++j)
        acc[i][j] = __builtin_amdgcn_mfma_f32_16x16x32_bf16(af[i], bfr[j], acc[i][j], 0, 0, 0);
  }

  if (MODE == 2) {
#pragma unroll
    for (int i = 0; i < 4; ++i) {
      const int m = m0 + wm + i * 16 + (l >> 4) * 4;
#pragma unroll
      for (int j = 0; j < NT; ++j) {
        const int n = n0 + wn + j * 16 + fr;
#pragma unroll
        for (int r = 0; r < 4; ++r) Cf[(size_t)(m + r) * 1024 + n] = acc[i][j][r];
      }
    }
  } else if (n0 < 2048) {
#pragma unroll
    for (int i = 0; i < 4; ++i) {
      const int m = m0 + wm + i * 16 + (l >> 4) * 4;
#pragma unroll
      for (int j = 0; j < NT; ++j) {
        const int n = n0 + wn + j * 16 + fr;
#pragma unroll
        for (int r = 0; r < 4; ++r) Cq[(size_t)(m + r) * 3072 + n] = (bf16_t)acc[i][j][r];
      }
    }
  } else {
#pragma unroll
    for (int i = 0; i < 4; ++i) {
      const int mb = m0 + wm + i * 16 + (l >> 4) * 4;
      const int bb = mb >> 11, ss = mb & 2047;
#pragma unroll
      for (int j = 0; j < NT; ++j) {
        const int nn = n0 - 2048 + wn + j * 16 + fr;
        const int hh = nn >> 6, dd = nn & 63;
        bf16x4 pk;
#pragma unroll
        for (int r = 0; r < 4; ++r) pk[r] = (bf16_t)acc[i][j][r];
        *(bf16x4*)(Cvt + (size_t)((bb * 16 + hh) * 64 + dd) * 2048 + ss) = pk;
      }
    }
  }
}

// ---- flash attention v6: 8-wave (512t) blocks, waves split (q-quarter x key-half) ----
// Uniform pairing (16+p, 15-p): 33 iters/block; grid 512 blocks = 2/CU -> 16 waves/CU
// (4 waves/SIMD, 2x v4/v5) to hide the per-iter LDS/MFMA latency chain. Per wave-iter:
// 16 q x 32 keys. Key-half partners (w, w^4) reduce partial O^T/li via LDS per phase.
__global__ __launch_bounds__(512, 4) void attn8w(const bf16_t* __restrict__ qkv,
                                                 const bf16_t* __restrict__ vt,
                                                 bf16_t* __restrict__ ctx) {
  const int p = blockIdx.y;       // 0..15
  const int bh = blockIdx.x;
  const int b = bh >> 4, h = bh & 15;
  const int tid = threadIdx.x, w = tid >> 6, l = tid & 63;
  const int fr = l & 15, fq = l >> 4;
  const int qq4 = w & 3;          // q quarter (16 q)
  const int kh = w >> 2;          // key half (32 keys)

  __shared__ __align__(16) bf16_t lK[2][64 * 64];   // 16 KB
  __shared__ __align__(16) bf16_t lV[2][64 * 64];   // 16 KB
  __shared__ __align__(16) bf16_t lP[8][16 * 40];   // 10.2 KB per-wave P^T
  __shared__ __align__(16) float lRed[4][16][68];   // 17.4 KB partials

  const bf16_t* kg = qkv + (size_t)b * 2048 * 3072 + 1024 + h * 64;
  const bf16_t* vg = vt + (size_t)(b * 16 + h) * 64 * 2048;

  const int srow = l >> 3;                // staging row within 8-row chunk
  const int swz = ((l & 7) ^ srow) * 8;   // XOR-swizzled column
  const int xr = fr & 7;

  bf16x8 ones;
#pragma unroll
  for (int i = 0; i < 8; ++i) ones[i] = (bf16_t)1.0f;

#pragma unroll 1
  for (int phase = 0; phase < 2; ++phase) {
    const int qt = (phase == 0) ? (16 + p) : (15 - p);
    const int q0 = qt * 64;
    const int qw = q0 + qq4 * 16;   // this wave's 16-q base

    bf16x8 qf[2];
#pragma unroll
    for (int ks = 0; ks < 2; ++ks)
      qf[ks] = *(const bf16x8*)(qkv + (size_t)(b * 2048 + qw + fr) * 3072 +
                                h * 64 + ks * 32 + fq * 8);

    f32x4 o[4] = {};
    f32x4 liacc = {};

    {  // stage tile 0: wave w stages rows w*8..w*8+7 (1 async K + 1 async V)
      const int row = w * 8 + srow;
      async_load16(kg + (size_t)row * 3072 + swz, &lK[0][w * 512]);
      async_load16(vg + (size_t)row * 2048 + swz, &lV[0][w * 512]);
    }

    for (int kt = 0; kt <= qt; ++kt) {
      const int buf = kt & 1;
      __syncthreads();
      if (kt < qt) {
        const int row = w * 8 + srow;
        async_load16(kg + (size_t)((kt + 1) * 64 + row) * 3072 + swz, &lK[buf ^ 1][w * 512]);
        async_load16(vg + (size_t)row * 2048 + (kt + 1) * 64 + swz, &lV[buf ^ 1][w * 512]);
      }

      const int kb = kt * 64 + kh * 32;   // wave's global key base
      if (kb > qw + 15) continue;         // wave fully masked (above diagonal)

      // S^T[key][q] = K·Q^T over 32 keys x 16 q
      f32x4 s[2] = {};
#pragma unroll
      for (int t = 0; t < 2; ++t)
#pragma unroll
        for (int ks = 0; ks < 2; ++ks) {
          bf16x8 kf = *(const bf16x8*)&lK[buf][(kh * 32 + t * 16 + fr) * 64 +
                                              ((ks * 4 + fq) ^ xr) * 8];
          s[t] = __builtin_amdgcn_mfma_f32_16x16x32_bf16(kf, qf[ks], s[t], 0, 0, 0);
        }

      const int qq = qw + fr;
      const bool needmask = (kb + 31) > qw;
#pragma unroll
      for (int t = 0; t < 2; ++t) {
        bf16x4 pk;
#pragma unroll
        for (int r = 0; r < 4; ++r) {
          float v = fmaf(s[t][r], SCALE_LOG2E, -FIXED_MAX);
          if (needmask && (kb + t * 16 + fq * 4 + r > qq)) v = -1e30f;
          pk[r] = (bf16_t)__builtin_amdgcn_exp2f(v);
        }
        *(bf16x4*)&lP[w][fr * 40 + t * 16 + fq * 4] = pk;
      }

      // O^T += V^T·P ; li += ones·P  (per-wave lP: in-wave lgkm ordering, no barrier)
      bf16x8 pf = *(const bf16x8*)&lP[w][fr * 40 + fq * 8];
#pragma unroll
      for (int dt = 0; dt < 4; ++dt) {
        bf16x8 vf = *(const bf16x8*)&lV[buf][(dt * 16 + fr) * 64 + ((kh * 4 + fq) ^ xr) * 8];
        o[dt] = __builtin_amdgcn_mfma_f32_16x16x32_bf16(vf, pf, o[dt], 0, 0, 0);
      }
      liacc = __builtin_amdgcn_mfma_f32_16x16x32_bf16(ones, pf, liacc, 0, 0, 0);
    }

    // key-half reduction: kh=1 writes partials, kh=0 adds + stores
    __syncthreads();
    if (kh) {
#pragma unroll
      for (int dt = 0; dt < 4; ++dt)
        *(f32x4*)&lRed[qq4][fr][dt * 16 + fq * 4] = o[dt];
      if (fq == 0) lRed[qq4][fr][64] = liacc[0];
    }
    __syncthreads();
    if (!kh) {
      const float lsum = liacc[0] + lRed[qq4][fr][64];
      const float inv = 1.f / lsum;
      bf16_t* cb = ctx + (size_t)(b * 2048 + qw + fr) * 1024 + h * 64;
#pragma unroll
      for (int dt = 0; dt < 4; ++dt) {
        f32x4 v = o[dt] + *(f32x4*)&lRed[qq4][fr][dt * 16 + fq * 4];
        bf16x4 ov;
#pragma unroll
        for (int r = 0; r < 4; ++r) ov[r] = (bf16_t)(v[r] * inv);
        *(bf16x4*)(cb + dt * 16 + fq * 4) = ov;
      }
    }
  }
}

extern "C" void kernel_launch(void* const* d_in, const int* in_sizes, int n_in,
                              void* d_out, int out_size, void* d_ws, size_t ws_size,
                              hipStream_t stream) {
  const float* x  = (const float*)d_in[0];
  const float* q  = (const float*)d_in[1];
  const float* WQ = (const float*)d_in[2];
  const float* WK = (const float*)d_in[3];
  const float* WV = (const float*)d_in[4];
  const float* WO = (const float*)d_in[5];
  float* out = (float*)d_out;

  bf16_t* qb  = (bf16_t*)d_ws;
  bf16_t* xb  = qb + 4194304;
  bf16_t* wt  = xb + 4194304;
  bf16_t* qkv = wt + 4194304;
  bf16_t* vtp = qkv + (size_t)4096 * 3072;
  bf16_t* ctx = vtp + 4194304;

  prep<<<dim3(5120), 256, 0, stream>>>(x, q, WQ, WK, WV, WO, xb, qb, wt);
  gemm128<0><<<dim3(24, 32), 256, 0, stream>>>(qb, xb, wt, qkv, vtp, nullptr);
  attn8w<<<dim3(32, 16), 512, 0, stream>>>(qkv, vtp, ctx);
  gemm128<2><<<dim3(16, 32), 256, 0, stream>>>(ctx, ctx, wt + (size_t)3072 * 1024,
                                               nullptr, nullptr, out);
}

// Round 9
// 182.796 us; speedup vs baseline: 1.2509x; 1.0301x over previous
//
#include <hip/hip_runtime.h>

// Shapes (fixed): B=2, S=2048, D=1024, H=16, hd=64. M = B*S = 4096.
// ws layout (bf16 elems): qb[4M] | xb[4M] | wt[4M] | qkv[4096*3072] | vt[2][16][64][2048] | ctx[4M]

typedef __bf16 bf16_t;
typedef __attribute__((ext_vector_type(8))) __bf16 bf16x8;
typedef __attribute__((ext_vector_type(4))) __bf16 bf16x4;
typedef __attribute__((ext_vector_type(4))) float f32x4;

#define SCALE_LOG2E 0.045084220027780106f  // log2(e)/32
#define FIXED_MAX 8.0f

__device__ __forceinline__ void async_load16(const void* g, void* l) {
  __builtin_amdgcn_global_load_lds(
      (const __attribute__((address_space(1))) void*)g,
      (__attribute__((address_space(3))) void*)l, 16, 0, 0);
}

// ---- fused prep: blocks 0..4095 cast x/q_in; blocks 4096..5119 cast+transpose weights ----
__global__ void prep(const float* __restrict__ x, const float* __restrict__ q,
                     const float* __restrict__ w0, const float* __restrict__ w1,
                     const float* __restrict__ w2, const float* __restrict__ w3,
                     bf16_t* __restrict__ xb, bf16_t* __restrict__ qb,
                     bf16_t* __restrict__ wt) {
  const int bid = blockIdx.x;
  if (bid < 4096) {
    const float* src = (bid >= 2048) ? q : x;
    bf16_t* dst = (bid >= 2048) ? qb : xb;
    const size_t i = ((size_t)(bid & 2047) * 256 + threadIdx.x) * 8;
    float4 v0 = *(const float4*)(src + i);
    float4 v1 = *(const float4*)(src + i + 4);
    bf16x8 o;
    o[0] = (bf16_t)v0.x; o[1] = (bf16_t)v0.y; o[2] = (bf16_t)v0.z; o[3] = (bf16_t)v0.w;
    o[4] = (bf16_t)v1.x; o[5] = (bf16_t)v1.y; o[6] = (bf16_t)v1.z; o[7] = (bf16_t)v1.w;
    *(bf16x8*)(dst + i) = o;
  } else {
    const int wb = bid - 4096;
    const int z = wb >> 8;
    const float* W = z == 0 ? w0 : z == 1 ? w1 : z == 2 ? w2 : w3;
    bf16_t* dst = wt + (size_t)z * 1048576;
    const int r0 = ((wb >> 4) & 15) * 64, c0 = (wb & 15) * 64;
    __shared__ bf16_t t[64][72];
#pragma unroll
    for (int i = 0; i < 16; ++i) {
      int flat = i * 256 + threadIdx.x;
      int r = flat >> 6, c = flat & 63;
      t[c][r] = (bf16_t)W[(size_t)(r0 + r) * 1024 + c0 + c];
    }
    __syncthreads();
    const int c = threadIdx.x >> 2, seg = (threadIdx.x & 3) * 16;
    bf16x8 a = *(const bf16x8*)&t[c][seg];
    bf16x8 b = *(const bf16x8*)&t[c][seg + 8];
    bf16_t* drow = dst + (size_t)(c0 + c) * 1024 + r0 + seg;
    *(bf16x8*)drow = a;
    *(bf16x8*)(drow + 8) = b;
  }
}

// ---- GEMM, BK=64 single-buffer (2 barriers per 64-k: half the drains of BK=32) ----
// XOR-swizzled LDS (row stride 128B would be 16-way conflicted; swizzle makes reads 2-way=free).
// MODE 0: fused QKV 128x128 (3 blk/CU). MODE 2: out GEMM 128x64, fp32 (4 blk/CU).
template <int MODE>
__global__ __launch_bounds__(256, MODE == 2 ? 4 : 3) void gemm128(
    const bf16_t* __restrict__ Aq, const bf16_t* __restrict__ Ax,
    const bf16_t* __restrict__ Bt,
    bf16_t* __restrict__ Cq, bf16_t* __restrict__ Cvt, float* __restrict__ Cf) {
  constexpr int K = 1024;
  constexpr int NT = (MODE == 2) ? 2 : 4;
  constexpr int NROWS = NT * 32;
  const int n0 = blockIdx.x * NROWS;
  const int m0 = blockIdx.y * 128;
  const bf16_t* A = (MODE == 0 && n0 >= 1024) ? Ax : Aq;

  __shared__ bf16_t lA[128 * 64];    // 16 KB, swizzled
  __shared__ bf16_t lB[NROWS * 64];  // 16/8 KB, swizzled

  const int tid = threadIdx.x;
  const int w = tid >> 6, l = tid & 63;
  const int wm = (w & 1) * 64, wn = (w >> 1) * (NT * 16);
  const int fr = l & 15, fq = l >> 4;
  const int xr = fr & 7;
  const int srow = l >> 3;                 // 0..7 row within 8-row chunk
  const int swz = ((l & 7) ^ srow) * 8;    // XOR-swizzled source column

  const int gk0 = (fq ^ xr) * 8;           // ks=0 physical col group
  const int gk1 = ((4 + fq) ^ xr) * 8;     // ks=1

  f32x4 acc[4][NT] = {};

  for (int kt = 0; kt < K; kt += 64) {
    __syncthreads();
#pragma unroll
    for (int c = 0; c < 4; ++c) {
      const int ch = w * 4 + c;  // 16 chunks x 8 rows = 128 rows
      async_load16(A + (size_t)(m0 + ch * 8 + srow) * K + kt + swz, &lA[ch * 512]);
      if (NT == 4) {
        async_load16(Bt + (size_t)(n0 + ch * 8 + srow) * K + kt + swz, &lB[ch * 512]);
      } else if (c < 2) {
        const int bch = w * 2 + c;  // 8 chunks x 8 rows = 64 rows
        async_load16(Bt + (size_t)(n0 + bch * 8 + srow) * K + kt + swz, &lB[bch * 512]);
      }
    }
    __syncthreads();
    bf16x8 af[4][2], bfr[NT][2];
#pragma unroll
    for (int i = 0; i < 4; ++i) {
      const int row = (wm + i * 16 + fr) * 64;
      af[i][0] = *(const bf16x8*)&lA[row + gk0];
      af[i][1] = *(const bf16x8*)&lA[row + gk1];
    }
#pragma unroll
    for (int j = 0; j < NT; ++j) {
      const int row = (wn + j * 16 + fr) * 64;
      bfr[j][0] = *(const bf16x8*)&lB[row + gk0];
      bfr[j][1] = *(const bf16x8*)&lB[row + gk1];
    }
#pragma unroll
    for (int i = 0; i < 4; ++i)
#pragma unroll
      for (int j = 0; j < NT; ++j) {
        acc[i][j] = __builtin_amdgcn_mfma_f32_16x16x32_bf16(af[i][0], bfr[j][0], acc[i][j], 0, 0, 0);
        acc[i][j] = __builtin_amdgcn_mfma_f32_16x16x32_bf16(af[i][1], bfr[j][1], acc[i][j], 0, 0, 0);
      }
  }

  if (MODE == 2) {
#pragma unroll
    for (int i = 0; i < 4; ++i) {
      const int m = m0 + wm + i * 16 + fq * 4;
#pragma unroll
      for (int j = 0; j < NT; ++j) {
        const int n = n0 + wn + j * 16 + fr;
#pragma unroll
        for (int r = 0; r < 4; ++r) Cf[(size_t)(m + r) * 1024 + n] = acc[i][j][r];
      }
    }
  } else if (n0 < 2048) {
#pragma unroll
    for (int i = 0; i < 4; ++i) {
      const int m = m0 + wm + i * 16 + fq * 4;
#pragma unroll
      for (int j = 0; j < NT; ++j) {
        const int n = n0 + wn + j * 16 + fr;
#pragma unroll
        for (int r = 0; r < 4; ++r) Cq[(size_t)(m + r) * 3072 + n] = (bf16_t)acc[i][j][r];
      }
    }
  } else {
#pragma unroll
    for (int i = 0; i < 4; ++i) {
      const int mb = m0 + wm + i * 16 + fq * 4;
      const int bb = mb >> 11, ss = mb & 2047;
#pragma unroll
      for (int j = 0; j < NT; ++j) {
        const int nn = n0 - 2048 + wn + j * 16 + fr;
        const int hh = nn >> 6, dd = nn & 63;
        bf16x4 pk;
#pragma unroll
        for (int r = 0; r < 4; ++r) pk[r] = (bf16_t)acc[i][j][r];
        *(bf16x4*)(Cvt + (size_t)((bb * 16 + hh) * 64 + dd) * 2048 + ss) = pk;
      }
    }
  }
}

// ---- flash attention v7: v6 structure + kt-unroll-by-2 (const LDS bufs) + hoisted pointers ----
__global__ __launch_bounds__(512, 4) void attn8w(const bf16_t* __restrict__ qkv,
                                                 const bf16_t* __restrict__ vt,
                                                 bf16_t* __restrict__ ctx) {
  const int p = blockIdx.y;
  const int bh = blockIdx.x;
  const int b = bh >> 4, h = bh & 15;
  const int tid = threadIdx.x, w = tid >> 6, l = tid & 63;
  const int fr = l & 15, fq = l >> 4;
  const int qq4 = w & 3;          // q quarter (16 q)
  const int kh = w >> 2;          // key half (32 keys)

  __shared__ __align__(16) bf16_t lK[2][64 * 64];
  __shared__ __align__(16) bf16_t lV[2][64 * 64];
  __shared__ __align__(16) bf16_t lP[8][16 * 40];
  __shared__ __align__(16) float lRed[4][16][68];

  const bf16_t* kg = qkv + (size_t)b * 2048 * 3072 + 1024 + h * 64;
  const bf16_t* vg = vt + (size_t)(b * 16 + h) * 64 * 2048;

  const int srow = l >> 3;
  const int swz = ((l & 7) ^ srow) * 8;
  const int xr = fr & 7;

  // hoisted per-lane LDS offsets (elems); buf handled by unrolled constants
  const int kbase = (kh * 32 + fr) * 64;
  const int g0 = (fq ^ xr) * 8, g1 = ((4 + fq) ^ xr) * 8;     // K col groups ks=0/1
  const int vbase = fr * 64;
  const int vg0 = ((kh * 4 + fq) ^ xr) * 8;                   // V col group
  const int pwr = fr * 40 + fq * 4;                           // lP write base
  const int prd = fr * 40 + fq * 8;                           // lP read base
  bf16_t* lPw = &lP[w][0];

  bf16x8 ones;
#pragma unroll
  for (int i = 0; i < 8; ++i) ones[i] = (bf16_t)1.0f;

#pragma unroll 1
  for (int phase = 0; phase < 2; ++phase) {
    const int qt = (phase == 0) ? (16 + p) : (15 - p);
    const int qw = qt * 64 + qq4 * 16;

    bf16x8 qf[2];
#pragma unroll
    for (int ks = 0; ks < 2; ++ks)
      qf[ks] = *(const bf16x8*)(qkv + (size_t)(b * 2048 + qw + fr) * 3072 +
                                h * 64 + ks * 32 + fq * 8);

    f32x4 o[4] = {};
    f32x4 liacc = {};

    // running prefetch pointers (wave stages 8 rows of K and V)
    const bf16_t* kp = kg + (size_t)(w * 8 + srow) * 3072 + swz;
    const bf16_t* vp = vg + (size_t)(w * 8 + srow) * 2048 + swz;

    if (phase == 1) __syncthreads();
    async_load16(kp, &lK[0][w * 512]);
    async_load16(vp, &lV[0][w * 512]);
    kp += 64 * 3072;
    vp += 64;

    auto compute = [&](int kt, int buf) {
      const int kb = kt * 64 + kh * 32;
      if (kb > qw + 15) return;  // wave fully masked (above diagonal)
      const bf16_t* lKb = &lK[buf][0];
      const bf16_t* lVb = &lV[buf][0];
      f32x4 s[2] = {};
#pragma unroll
      for (int t = 0; t < 2; ++t) {
        bf16x8 k0 = *(const bf16x8*)&lKb[kbase + t * 1024 + g0];
        bf16x8 k1 = *(const bf16x8*)&lKb[kbase + t * 1024 + g1];
        s[t] = __builtin_amdgcn_mfma_f32_16x16x32_bf16(k0, qf[0], s[t], 0, 0, 0);
        s[t] = __builtin_amdgcn_mfma_f32_16x16x32_bf16(k1, qf[1], s[t], 0, 0, 0);
      }
      const int qq = qw + fr;
      const bool needmask = (kb + 31) > qw;
#pragma unroll
      for (int t = 0; t < 2; ++t) {
        bf16x4 pk;
#pragma unroll
        for (int r = 0; r < 4; ++r) {
          float v = fmaf(s[t][r], SCALE_LOG2E, -FIXED_MAX);
          if (needmask && (kb + t * 16 + fq * 4 + r > qq)) v = -1e30f;
          pk[r] = (bf16_t)__builtin_amdgcn_exp2f(v);
        }
        *(bf16x4*)&lPw[pwr + t * 16] = pk;
      }
      bf16x8 pf = *(const bf16x8*)&lPw[prd];
#pragma unroll
      for (int dt = 0; dt < 4; ++dt) {
        bf16x8 vf = *(const bf16x8*)&lVb[vbase + dt * 1024 + vg0];
        o[dt] = __builtin_amdgcn_mfma_f32_16x16x32_bf16(vf, pf, o[dt], 0, 0, 0);
      }
      liacc = __builtin_amdgcn_mfma_f32_16x16x32_bf16(ones, pf, liacc, 0, 0, 0);
    };

    int kt = 0;
#pragma unroll 1
    while (true) {
      __syncthreads();
      if (kt < qt) {
        async_load16(kp, &lK[1][w * 512]);
        async_load16(vp, &lV[1][w * 512]);
        kp += 64 * 3072; vp += 64;
      }
      compute(kt, 0);
      if (++kt > qt) break;
      __syncthreads();
      if (kt < qt) {
        async_load16(kp, &lK[0][w * 512]);
        async_load16(vp, &lV[0][w * 512]);
        kp += 64 * 3072; vp += 64;
      }
      compute(kt, 1);
      if (++kt > qt) break;
    }

    // key-half reduction: kh=1 writes partials, kh=0 adds + stores
    __syncthreads();
    if (kh) {
#pragma unroll
      for (int dt = 0; dt < 4; ++dt)
        *(f32x4*)&lRed[qq4][fr][dt * 16 + fq * 4] = o[dt];
      if (fq == 0) lRed[qq4][fr][64] = liacc[0];
    }
    __syncthreads();
    if (!kh) {
      const float lsum = liacc[0] + lRed[qq4][fr][64];
      const float inv = 1.f / lsum;
      bf16_t* cb = ctx + (size_t)(b * 2048 + qw + fr) * 1024 + h * 64;
#pragma unroll
      for (int dt = 0; dt < 4; ++dt) {
        f32x4 v = o[dt] + *(f32x4*)&lRed[qq4][fr][dt * 16 + fq * 4];
        bf16x4 ov;
#pragma unroll
        for (int r = 0; r < 4; ++r) ov[r] = (bf16_t)(v[r] * inv);
        *(bf16x4*)(cb + dt * 16 + fq * 4) = ov;
      }
    }
  }
}

extern "C" void kernel_launch(void* const* d_in, const int* in_sizes, int n_in,
                              void* d_out, int out_size, void* d_ws, size_t ws_size,
                              hipStream_t stream) {
  const float* x  = (const float*)d_in[0];
  const float* q  = (const float*)d_in[1];
  const float* WQ = (const float*)d_in[2];
  const float* WK = (const float*)d_in[3];
  const float* WV = (const float*)d_in[4];
  const float* WO = (const float*)d_in[5];
  float* out = (float*)d_out;

  bf16_t* qb  = (bf16_t*)d_ws;
  bf16_t* xb  = qb + 4194304;
  bf16_t* wt  = xb + 4194304;
  bf16_t* qkv = wt + 4194304;
  bf16_t* vtp = qkv + (size_t)4096 * 3072;
  bf16_t* ctx = vtp + 4194304;

  prep<<<dim3(5120), 256, 0, stream>>>(x, q, WQ, WK, WV, WO, xb, qb, wt);
  gemm128<0><<<dim3(24, 32), 256, 0, stream>>>(qb, xb, wt, qkv, vtp, nullptr);
  attn8w<<<dim3(32, 16), 512, 0, stream>>>(qkv, vtp, ctx);
  gemm128<2><<<dim3(16, 32), 256, 0, stream>>>(ctx, ctx, wt + (size_t)3072 * 1024,
                                               nullptr, nullptr, out);
}